// Round 2
// baseline (123.874 us; speedup 1.0000x reference)
//
#include <hip/hip_runtime.h>

typedef float v2f __attribute__((ext_vector_type(2)));

#define W_IMG   128
#define H_IMG   128
#define HW_IMG  16384
#define FX_C    128.0f
#define FY_C    128.0f
#define CX_C    64.0f
#define CY_C    64.0f
#define LOG2E_F 1.4426950408889634f
#define CHUNK   32

// ---------------------------------------------------------------------------
// Inline per-gaussian projection: {px, py, a2, op}, a2 = -0.5/var*log2(e).
// ---------------------------------------------------------------------------
__device__ __forceinline__ float4 proj_of(
    const float* __restrict__ pos, const float* __restrict__ opac,
    const float* __restrict__ scl, const float* __restrict__ qv,
    const float* __restrict__ tv, int i)
{
    float qw = qv[0], qx = qv[1], qy = qv[2], qz = qv[3];
    float qn = sqrtf(qw*qw + qx*qx + qy*qy + qz*qz);
    qw /= qn; qx /= qn; qy /= qn; qz /= qn;

    float R00 = 1.f - 2.f*(qy*qy + qz*qz), R01 = 2.f*(qx*qy - qz*qw), R02 = 2.f*(qx*qz + qy*qw);
    float R10 = 2.f*(qx*qy + qz*qw), R11 = 1.f - 2.f*(qx*qx + qz*qz), R12 = 2.f*(qy*qz - qx*qw);
    float R20 = 2.f*(qx*qz - qy*qw), R21 = 2.f*(qy*qz + qx*qw), R22 = 1.f - 2.f*(qx*qx + qy*qy);

    float x = pos[3*i + 0];
    float y = pos[3*i + 1];
    float z = pos[3*i + 2];

    float cx = R00*x + R01*y + R02*z + tv[0];
    float cy = R10*x + R11*y + R12*z + tv[1];
    float cz = R20*x + R21*y + R22*z + tv[2];

    float px = cx / cz * FX_C + CX_C;
    float py = cy / cz * FY_C + CY_C;

    float s   = scl[i];
    float a2  = (-0.5f / (s * s)) * LOG2E_F;

    float4 r; r.x = px; r.y = py; r.z = a2; r.w = opac[i];
    return r;
}

// ---------------------------------------------------------------------------
// Fused hot kernel: factor tables computed on the fly into LDS, then
// register-tiled rank-1 accumulation out of LDS.
// Block = 128x * 8y px, thread tile 2x*2y, 4 waves. grid = (16, S).
// Per chunk of 32 gaussians: stage proj (32 thr) -> U[32][128] (16 KB) and
// V[32][8] (1 KB) in LDS -> inner loop: ds_read_b64 (2-way alias, free) +
// broadcast b64 + uniform scalar color loads + 10 packed VALU per 4 px.
// LDS 17.9 KB + VGPR<=64 -> 8 blocks/CU (32 waves/CU, full occupancy);
// grid 16*128 = 2048 blocks = 8/CU. Accumulation order per pixel is
// unchanged vs the 64-chunk version (single running accumulator, j
// ascending through the segment) -> bit-identical numerics.
// ---------------------------------------------------------------------------
__global__ __launch_bounds__(256, 8) void gemm_fused(
    const float* __restrict__ pos, const float* __restrict__ col,
    const float* __restrict__ opac, const float* __restrict__ scl,
    const float* __restrict__ qv, const float* __restrict__ tv,
    float4* __restrict__ part, int segLen)
{
    __shared__ __align__(16) float  U_lds[CHUNK * 128];   // 16 KB
    __shared__ __align__(16) float  V_lds[CHUNK * 8];     // 1 KB
    __shared__ __align__(16) float4 P_lds[CHUNK];         // 0.5 KB

    int tid = threadIdx.x;
    int xt  = tid & 63;                   // x-pair index within the 128-px row
    int wy  = (tid >> 6) * 2;             // thread's y offset within block tile
    int yb  = blockIdx.x * 8;             // block's y base
    int g0  = blockIdx.y * segLen;

    v2f ar0 = 0.f, ag0 = 0.f, ab0 = 0.f, ad0 = 0.f;
    v2f ar1 = 0.f, ag1 = 0.f, ab1 = 0.f, ad1 = 0.f;

    for (int c0 = 0; c0 < segLen; c0 += CHUNK) {
        int cc = (segLen - c0 < CHUNK) ? (segLen - c0) : CHUNK;

        __syncthreads();                           // LDS reuse guard
        if (tid < cc)
            P_lds[tid] = proj_of(pos, opac, scl, qv, tv, g0 + c0 + tid);
        __syncthreads();

        // Stage U: e = g*128 + x, lanes consecutive -> conflict-free writes;
        // P_lds[e>>7] is wave-uniform -> broadcast read. 16 iterations.
        for (int e = tid; e < cc * 128; e += 256) {
            float4 p = P_lds[e >> 7];
            float dx = (float)(e & 127) - p.x;
            U_lds[e] = p.w * __builtin_amdgcn_exp2f(p.z * dx * dx);
        }
        // Stage V: e = g*8 + y (block-local y). Single iteration.
        for (int e = tid; e < cc * 8; e += 256) {
            float4 p = P_lds[e >> 3];
            float dy = (float)(yb + (e & 7)) - p.y;
            V_lds[e] = __builtin_amdgcn_exp2f(p.z * dy * dy);
        }
        __syncthreads();

        const float* __restrict__ colp = col + 3 * (g0 + c0);  // uniform base

        #pragma unroll 8
        for (int j = 0; j < cc; ++j) {
            v2f   u = *(const v2f*)(U_lds + j * 128 + 2 * xt);  // ds_read_b64
            v2f   v = *(const v2f*)(V_lds + j * 8 + wy);        // broadcast b64
            float cr = colp[3*j + 0];                           // uniform -> s_load
            float cg = colp[3*j + 1];
            float cb = colp[3*j + 2];

            v2f w0 = u * v.x;
            v2f w1 = u * v.y;

            ar0 += w0 * cr; ag0 += w0 * cg; ab0 += w0 * cb; ad0 += w0;
            ar1 += w1 * cr; ag1 += w1 * cg; ab1 += w1 * cb; ad1 += w1;
        }
    }

    size_t segBase = (size_t)blockIdx.y * HW_IMG + 2 * xt;
    {
        size_t b = segBase + (size_t)(yb + wy + 0) * 128;
        float4 o0; o0.x = ar0.x; o0.y = ag0.x; o0.z = ab0.x; o0.w = ad0.x;
        float4 o1; o1.x = ar0.y; o1.y = ag0.y; o1.z = ab0.y; o1.w = ad0.y;
        part[b] = o0; part[b + 1] = o1;
    }
    {
        size_t b = segBase + (size_t)(yb + wy + 1) * 128;
        float4 o0; o0.x = ar1.x; o0.y = ag1.x; o0.z = ab1.x; o0.w = ad1.x;
        float4 o1; o1.x = ar1.y; o1.y = ag1.y; o1.z = ab1.y; o1.w = ad1.y;
        part[b] = o0; part[b + 1] = o1;
    }
}

// ---------------------------------------------------------------------------
// Fallback hot kernel (tiny-workspace path only): direct 2-D evaluation.
// ---------------------------------------------------------------------------
__global__ __launch_bounds__(256) void render_fb(
    const float* __restrict__ pos, const float* __restrict__ col,
    const float* __restrict__ opac, const float* __restrict__ scl,
    const float* __restrict__ qv, const float* __restrict__ tv,
    float4* __restrict__ part, int segLen)
{
    int p = blockIdx.x * 256 + threadIdx.x;
    float X = (float)(p & (W_IMG - 1));
    float Y = (float)(p >> 7);

    int g0 = blockIdx.y * segLen;
    float nr = 0.f, ng = 0.f, nb = 0.f, den = 0.f;
    for (int j = 0; j < segLen; ++j) {
        int g = g0 + j;
        float4 pg = proj_of(pos, opac, scl, qv, tv, g);
        float dx = X - pg.x;
        float dy = Y - pg.y;
        float d2 = fmaf(dx, dx, dy * dy);
        float e  = pg.w * __builtin_amdgcn_exp2f(pg.z * d2);
        nr  = fmaf(e, col[3*g+0], nr);
        ng  = fmaf(e, col[3*g+1], ng);
        nb  = fmaf(e, col[3*g+2], nb);
        den += e;
    }
    float4 o; o.x = nr; o.y = ng; o.z = nb; o.w = den;
    part[(size_t)blockIdx.y * HW_IMG + p] = o;
}

// ---------------------------------------------------------------------------
// Finalize: reduce segments, add n_chunks*EPS, divide, tiled/transposed fp32
// output: out[t, c, s/tile, s%tile], p = t*step + s, step = tile^2.
// ---------------------------------------------------------------------------
__global__ __launch_bounds__(256) void finalize_kernel(
    const float4* __restrict__ part, float* __restrict__ out,
    const int* __restrict__ chunk_gauss_p, const int* __restrict__ tile_hw_p,
    int N, int nseg)
{
    int p = blockIdx.x * 256 + threadIdx.x;

    float nr = 0.f, ng = 0.f, nb = 0.f, den = 0.f;
    #pragma unroll 8
    for (int s = 0; s < nseg; ++s) {
        float4 v = part[(size_t)s * HW_IMG + p];
        nr += v.x; ng += v.y; nb += v.z; den += v.w;
    }

    int cg = chunk_gauss_p[0];
    int n_chunks = (cg > 0) ? (N / cg) : 0;
    den += (float)n_chunks * 1e-8f;   // EPS added once per scan chunk

    int th   = tile_hw_p[0];
    int step = th * th;
    if (step <= 0 || step > HW_IMG) { th = 64; step = th * th; }
    int t  = p / step;
    int s2 = p - t * step;
    size_t base = (size_t)t * 3 * step + s2;

    out[base]            = nr / den;
    out[base + step]     = ng / den;
    out[base + 2 * step] = nb / den;
}

extern "C" void kernel_launch(void* const* d_in, const int* in_sizes, int n_in,
                              void* d_out, int out_size, void* d_ws, size_t ws_size,
                              hipStream_t stream)
{
    const float* pos  = (const float*)d_in[0];
    const float* col  = (const float*)d_in[1];
    const float* opac = (const float*)d_in[2];
    const float* scl  = (const float*)d_in[3];
    const float* qv   = (const float*)d_in[4];
    const float* tv   = (const float*)d_in[5];
    const int* tile_hw_p     = (const int*)d_in[6];
    const int* chunk_gauss_p = (const int*)d_in[7];

    int N = in_sizes[2];                 // one opacity per gaussian

    // Workspace: only part[S * HW] float4 (factors live in LDS).
    int S = 0;
    for (int cand = 128; cand >= 8; cand >>= 1) {
        if (N % cand == 0 &&
            (size_t)cand * HW_IMG * 16 <= ws_size) { S = cand; break; }
    }

    float4* part = (float4*)d_ws;

    if (S > 0) {
        dim3 grid(H_IMG / 8, S);
        gemm_fused<<<grid, 256, 0, stream>>>(
            pos, col, opac, scl, qv, tv, part, N / S);

        finalize_kernel<<<HW_IMG / 256, 256, 0, stream>>>(
            part, (float*)d_out, chunk_gauss_p, tile_hw_p, N, S);
    } else {
        int nseg = 16;
        while (nseg > 1 &&
               ((size_t)nseg * HW_IMG * 16 > ws_size || (N % nseg) != 0))
            nseg >>= 1;

        dim3 grid(HW_IMG / 256, nseg);
        render_fb<<<grid, 256, 0, stream>>>(pos, col, opac, scl, qv, tv, part, N / nseg);

        finalize_kernel<<<HW_IMG / 256, 256, 0, stream>>>(
            part, (float*)d_out, chunk_gauss_p, tile_hw_p, N, nseg);
    }
}

// Round 3
// 122.665 us; speedup vs baseline: 1.0099x; 1.0099x over previous
//
#include <hip/hip_runtime.h>

typedef float v2f __attribute__((ext_vector_type(2)));

#define W_IMG   128
#define H_IMG   128
#define HW_IMG  16384
#define FX_C    128.0f
#define FY_C    128.0f
#define CX_C    64.0f
#define CY_C    64.0f
#define LOG2E_F 1.4426950408889634f
#define CHUNK   32

// ---------------------------------------------------------------------------
// Inline per-gaussian projection: {px, py, a2, op}, a2 = -0.5/var*log2(e).
// ---------------------------------------------------------------------------
__device__ __forceinline__ float4 proj_of(
    const float* __restrict__ pos, const float* __restrict__ opac,
    const float* __restrict__ scl, const float* __restrict__ qv,
    const float* __restrict__ tv, int i)
{
    float qw = qv[0], qx = qv[1], qy = qv[2], qz = qv[3];
    float qn = sqrtf(qw*qw + qx*qx + qy*qy + qz*qz);
    qw /= qn; qx /= qn; qy /= qn; qz /= qn;

    float R00 = 1.f - 2.f*(qy*qy + qz*qz), R01 = 2.f*(qx*qy - qz*qw), R02 = 2.f*(qx*qz + qy*qw);
    float R10 = 2.f*(qx*qy + qz*qw), R11 = 1.f - 2.f*(qx*qx + qz*qz), R12 = 2.f*(qy*qz - qx*qw);
    float R20 = 2.f*(qx*qz - qy*qw), R21 = 2.f*(qy*qz + qx*qw), R22 = 1.f - 2.f*(qx*qx + qy*qy);

    float x = pos[3*i + 0];
    float y = pos[3*i + 1];
    float z = pos[3*i + 2];

    float cx = R00*x + R01*y + R02*z + tv[0];
    float cy = R10*x + R11*y + R12*z + tv[1];
    float cz = R20*x + R21*y + R22*z + tv[2];

    float px = cx / cz * FX_C + CX_C;
    float py = cy / cz * FY_C + CY_C;

    float s   = scl[i];
    float a2  = (-0.5f / (s * s)) * LOG2E_F;

    float4 r; r.x = px; r.y = py; r.z = a2; r.w = opac[i];
    return r;
}

// ---------------------------------------------------------------------------
// Fused hot kernel: factor tables computed on the fly into LDS, then
// register-tiled rank-1 accumulation out of LDS.
// Block = 128x * 16y px, 512 threads (8 waves), thread tile 2x*2y.
// grid = (8, S) = 1024 blocks = 4 blocks/CU = 32 waves/CU (full occupancy).
// Per chunk of 32 gaussians:
//   wave0 (tid<32) computes proj -> P_lds; wave1 (tid 64..159) stages the
//   chunk's colors into C_lds (float4/gaussian, broadcast-readable);
//   then all 512 threads stage U[32][128] (8 iters) and V[32][16] (1 iter);
//   inner loop per j: ds_read_b64 (u, 2-way alias free) + b64 broadcast (v)
//   + b128 broadcast (colors) + 10 packed VALU for 4 px.
// LDS 19.5 KB -> 4 blocks/CU; no per-j s_loads left in the hot loop.
// U-staging amortized over 16 rows (1152 exp2-elements/gaussian, same as
// the original 48.5us kernel, half of the R2 regression).
// Per-pixel accumulation order identical to prior versions -> bit-identical.
// ---------------------------------------------------------------------------
__global__ __launch_bounds__(512, 8) void gemm_fused(
    const float* __restrict__ pos, const float* __restrict__ col,
    const float* __restrict__ opac, const float* __restrict__ scl,
    const float* __restrict__ qv, const float* __restrict__ tv,
    float4* __restrict__ part, int segLen)
{
    __shared__ __align__(16) float  U_lds[CHUNK * 128];   // 16 KB
    __shared__ __align__(16) float  V_lds[CHUNK * 16];    // 2 KB
    __shared__ __align__(16) float  C_lds[CHUNK * 4];     // 0.5 KB {r,g,b,-}
    __shared__ __align__(16) float4 P_lds[CHUNK];         // 0.5 KB

    int tid = threadIdx.x;
    int xt  = tid & 63;                   // x-pair index within the 128-px row
    int wy  = (tid >> 6) * 2;             // thread's y offset (0,2,...,14)
    int yb  = blockIdx.x * 16;            // block's y base
    int g0  = blockIdx.y * segLen;

    v2f ar0 = 0.f, ag0 = 0.f, ab0 = 0.f, ad0 = 0.f;
    v2f ar1 = 0.f, ag1 = 0.f, ab1 = 0.f, ad1 = 0.f;

    for (int c0 = 0; c0 < segLen; c0 += CHUNK) {
        int cc = (segLen - c0 < CHUNK) ? (segLen - c0) : CHUNK;

        __syncthreads();                           // LDS reuse guard
        if (tid < cc) {
            P_lds[tid] = proj_of(pos, opac, scl, qv, tv, g0 + c0 + tid);
        } else if (tid >= 64 && tid < 64 + 3 * cc) {
            // wave 1 stages colors concurrently with wave 0's projection
            int e = tid - 64;                      // 0 .. 3*cc-1
            int g = e / 3;                         // const-div -> magic mul
            C_lds[g * 4 + (e - 3 * g)] = col[3 * (g0 + c0) + e];
        }
        __syncthreads();

        // Stage U: e = g*128 + x, lanes consecutive -> conflict-free writes;
        // P_lds[e>>7] is wave-uniform/2-way -> broadcast read. 8 iterations.
        for (int e = tid; e < cc * 128; e += 512) {
            float4 p = P_lds[e >> 7];
            float dx = (float)(e & 127) - p.x;
            U_lds[e] = p.w * __builtin_amdgcn_exp2f(p.z * dx * dx);
        }
        // Stage V: e = g*16 + y (block-local y). Single iteration.
        for (int e = tid; e < cc * 16; e += 512) {
            float4 p = P_lds[e >> 4];
            float dy = (float)(yb + (e & 15)) - p.y;
            V_lds[e] = __builtin_amdgcn_exp2f(p.z * dy * dy);
        }
        __syncthreads();

        #pragma unroll 8
        for (int j = 0; j < cc; ++j) {
            v2f    u  = *(const v2f*)(U_lds + j * 128 + 2 * xt);  // ds_read_b64
            v2f    v  = *(const v2f*)(V_lds + j * 16 + wy);       // broadcast b64
            float4 c4 = *(const float4*)(C_lds + 4 * j);          // broadcast b128
            float cr = c4.x;
            float cg = c4.y;
            float cb = c4.z;

            v2f w0 = u * v.x;
            v2f w1 = u * v.y;

            ar0 += w0 * cr; ag0 += w0 * cg; ab0 += w0 * cb; ad0 += w0;
            ar1 += w1 * cr; ag1 += w1 * cg; ab1 += w1 * cb; ad1 += w1;
        }
    }

    size_t segBase = (size_t)blockIdx.y * HW_IMG + 2 * xt;
    {
        size_t b = segBase + (size_t)(yb + wy + 0) * 128;
        float4 o0; o0.x = ar0.x; o0.y = ag0.x; o0.z = ab0.x; o0.w = ad0.x;
        float4 o1; o1.x = ar0.y; o1.y = ag0.y; o1.z = ab0.y; o1.w = ad0.y;
        part[b] = o0; part[b + 1] = o1;
    }
    {
        size_t b = segBase + (size_t)(yb + wy + 1) * 128;
        float4 o0; o0.x = ar1.x; o0.y = ag1.x; o0.z = ab1.x; o0.w = ad1.x;
        float4 o1; o1.x = ar1.y; o1.y = ag1.y; o1.z = ab1.y; o1.w = ad1.y;
        part[b] = o0; part[b + 1] = o1;
    }
}

// ---------------------------------------------------------------------------
// Fallback hot kernel (tiny-workspace path only): direct 2-D evaluation.
// ---------------------------------------------------------------------------
__global__ __launch_bounds__(256) void render_fb(
    const float* __restrict__ pos, const float* __restrict__ col,
    const float* __restrict__ opac, const float* __restrict__ scl,
    const float* __restrict__ qv, const float* __restrict__ tv,
    float4* __restrict__ part, int segLen)
{
    int p = blockIdx.x * 256 + threadIdx.x;
    float X = (float)(p & (W_IMG - 1));
    float Y = (float)(p >> 7);

    int g0 = blockIdx.y * segLen;
    float nr = 0.f, ng = 0.f, nb = 0.f, den = 0.f;
    for (int j = 0; j < segLen; ++j) {
        int g = g0 + j;
        float4 pg = proj_of(pos, opac, scl, qv, tv, g);
        float dx = X - pg.x;
        float dy = Y - pg.y;
        float d2 = fmaf(dx, dx, dy * dy);
        float e  = pg.w * __builtin_amdgcn_exp2f(pg.z * d2);
        nr  = fmaf(e, col[3*g+0], nr);
        ng  = fmaf(e, col[3*g+1], ng);
        nb  = fmaf(e, col[3*g+2], nb);
        den += e;
    }
    float4 o; o.x = nr; o.y = ng; o.z = nb; o.w = den;
    part[(size_t)blockIdx.y * HW_IMG + p] = o;
}

// ---------------------------------------------------------------------------
// Finalize: reduce segments, add n_chunks*EPS, divide, tiled/transposed fp32
// output: out[t, c, s/tile, s%tile], p = t*step + s, step = tile^2.
// ---------------------------------------------------------------------------
__global__ __launch_bounds__(256) void finalize_kernel(
    const float4* __restrict__ part, float* __restrict__ out,
    const int* __restrict__ chunk_gauss_p, const int* __restrict__ tile_hw_p,
    int N, int nseg)
{
    int p = blockIdx.x * 256 + threadIdx.x;

    float nr = 0.f, ng = 0.f, nb = 0.f, den = 0.f;
    #pragma unroll 8
    for (int s = 0; s < nseg; ++s) {
        float4 v = part[(size_t)s * HW_IMG + p];
        nr += v.x; ng += v.y; nb += v.z; den += v.w;
    }

    int cg = chunk_gauss_p[0];
    int n_chunks = (cg > 0) ? (N / cg) : 0;
    den += (float)n_chunks * 1e-8f;   // EPS added once per scan chunk

    int th   = tile_hw_p[0];
    int step = th * th;
    if (step <= 0 || step > HW_IMG) { th = 64; step = th * th; }
    int t  = p / step;
    int s2 = p - t * step;
    size_t base = (size_t)t * 3 * step + s2;

    out[base]            = nr / den;
    out[base + step]     = ng / den;
    out[base + 2 * step] = nb / den;
}

extern "C" void kernel_launch(void* const* d_in, const int* in_sizes, int n_in,
                              void* d_out, int out_size, void* d_ws, size_t ws_size,
                              hipStream_t stream)
{
    const float* pos  = (const float*)d_in[0];
    const float* col  = (const float*)d_in[1];
    const float* opac = (const float*)d_in[2];
    const float* scl  = (const float*)d_in[3];
    const float* qv   = (const float*)d_in[4];
    const float* tv   = (const float*)d_in[5];
    const int* tile_hw_p     = (const int*)d_in[6];
    const int* chunk_gauss_p = (const int*)d_in[7];

    int N = in_sizes[2];                 // one opacity per gaussian

    // Workspace: only part[S * HW] float4 (factors live in LDS).
    int S = 0;
    for (int cand = 128; cand >= 8; cand >>= 1) {
        if (N % cand == 0 &&
            (size_t)cand * HW_IMG * 16 <= ws_size) { S = cand; break; }
    }

    float4* part = (float4*)d_ws;

    if (S > 0) {
        dim3 grid(H_IMG / 16, S);
        gemm_fused<<<grid, 512, 0, stream>>>(
            pos, col, opac, scl, qv, tv, part, N / S);

        finalize_kernel<<<HW_IMG / 256, 256, 0, stream>>>(
            part, (float*)d_out, chunk_gauss_p, tile_hw_p, N, S);
    } else {
        int nseg = 16;
        while (nseg > 1 &&
               ((size_t)nseg * HW_IMG * 16 > ws_size || (N % nseg) != 0))
            nseg >>= 1;

        dim3 grid(HW_IMG / 256, nseg);
        render_fb<<<grid, 256, 0, stream>>>(pos, col, opac, scl, qv, tv, part, N / nseg);

        finalize_kernel<<<HW_IMG / 256, 256, 0, stream>>>(
            part, (float*)d_out, chunk_gauss_p, tile_hw_p, N, nseg);
    }
}

// Round 4
// 117.248 us; speedup vs baseline: 1.0565x; 1.0462x over previous
//
#include <hip/hip_runtime.h>

typedef float v2f __attribute__((ext_vector_type(2)));

#define W_IMG   128
#define H_IMG   128
#define HW_IMG  16384
#define FX_C    128.0f
#define FY_C    128.0f
#define CX_C    64.0f
#define CY_C    64.0f
#define LOG2E_F 1.4426950408889634f
#define CHUNK   64

// Packed dual-FP32 (VOP3P, gfx90a+/gfx950). All operands are genuine v2f
// register pairs -> plain pair syntax, no opsel.
__device__ __forceinline__ v2f pk_mul(v2f a, v2f b) {
    v2f d; asm("v_pk_mul_f32 %0, %1, %2" : "=v"(d) : "v"(a), "v"(b)); return d;
}
__device__ __forceinline__ void pk_fma(v2f& a, v2f m, v2f c) {
    asm("v_pk_fma_f32 %0, %1, %2, %0" : "+v"(a) : "v"(m), "v"(c));
}
__device__ __forceinline__ void pk_add(v2f& a, v2f b) {
    asm("v_pk_add_f32 %0, %1, %0" : "+v"(a) : "v"(b));
}

// ---------------------------------------------------------------------------
// Inline per-gaussian projection: {px, py, a2, op}, a2 = -0.5/var*log2(e).
// ---------------------------------------------------------------------------
__device__ __forceinline__ float4 proj_of(
    const float* __restrict__ pos, const float* __restrict__ opac,
    const float* __restrict__ scl, const float* __restrict__ qv,
    const float* __restrict__ tv, int i)
{
    float qw = qv[0], qx = qv[1], qy = qv[2], qz = qv[3];
    float qn = sqrtf(qw*qw + qx*qx + qy*qy + qz*qz);
    qw /= qn; qx /= qn; qy /= qn; qz /= qn;

    float R00 = 1.f - 2.f*(qy*qy + qz*qz), R01 = 2.f*(qx*qy - qz*qw), R02 = 2.f*(qx*qz + qy*qw);
    float R10 = 2.f*(qx*qy + qz*qw), R11 = 1.f - 2.f*(qx*qx + qz*qz), R12 = 2.f*(qy*qz - qx*qw);
    float R20 = 2.f*(qx*qz - qy*qw), R21 = 2.f*(qy*qz + qx*qw), R22 = 1.f - 2.f*(qx*qx + qy*qy);

    float x = pos[3*i + 0];
    float y = pos[3*i + 1];
    float z = pos[3*i + 2];

    float cx = R00*x + R01*y + R02*z + tv[0];
    float cy = R10*x + R11*y + R12*z + tv[1];
    float cz = R20*x + R21*y + R22*z + tv[2];

    float px = cx / cz * FX_C + CX_C;
    float py = cy / cz * FY_C + CY_C;

    float s   = scl[i];
    float a2  = (-0.5f / (s * s)) * LOG2E_F;

    float4 r; r.x = px; r.y = py; r.z = a2; r.w = opac[i];
    return r;
}

// ---------------------------------------------------------------------------
// Fused hot kernel, j-pair-packed VOP3P version.
// Block = 128x * 16y px, 256 threads, thread tile 2x*4y. grid = (8, S).
// LDS layouts chosen so every multiply operand is a v2f j-pair:
//   U2[jp][x][2]  (32 KB): b128 at (jp,2*xt) = {x0j0,x0j1,x1j0,x1j1};
//                 x is the lane-fast read axis -> inherent-optimal b128, no swizzle.
//   V_t[y][j]     (4 KB) : b128 broadcast = 4 j's (2 jp) for one y.
//   C_t[ch][j]    (768 B): b128 broadcast = 4 j's per channel.
// Inner loop per 4-j group: 9 DS reads + 80 v_pk ops for 8 px (2.5 pk/px,
// half the scalar version). Accumulators keep even/odd-j partial sums,
// horizontally added in the epilogue.
// LDS 37.8 KB -> 4 blocks/CU; launch_bounds(256,4) caps VGPR at 128 (~110 used).
// ---------------------------------------------------------------------------
__global__ __launch_bounds__(256, 4) void gemm_fused(
    const float* __restrict__ pos, const float* __restrict__ col,
    const float* __restrict__ opac, const float* __restrict__ scl,
    const float* __restrict__ qv, const float* __restrict__ tv,
    float4* __restrict__ part, int segLen)
{
    __shared__ __align__(16) float  U2[(CHUNK/2) * 128 * 2];  // 32 KB [jp][x][j&1]
    __shared__ __align__(16) float  V_t[16 * CHUNK];          // 4 KB  [y][j]
    __shared__ __align__(16) float  C_t[3 * CHUNK];           // 768 B [ch][j]
    __shared__ __align__(16) float4 P_lds[CHUNK];             // 1 KB

    int tid = threadIdx.x;
    int xt  = tid & 63;                   // x-pair index within the 128-px row
    int wy  = (tid >> 6) * 4;             // thread's y offset (0,4,8,12)
    int yb  = blockIdx.x * 16;            // block's y base
    int g0  = blockIdx.y * segLen;

    v2f accR[2][4], accG[2][4], accB[2][4], accD[2][4];  // [xi][yi], j-pair lanes
    #pragma unroll
    for (int xi = 0; xi < 2; ++xi)
        #pragma unroll
        for (int yi = 0; yi < 4; ++yi) {
            accR[xi][yi] = 0.f; accG[xi][yi] = 0.f;
            accB[xi][yi] = 0.f; accD[xi][yi] = 0.f;
        }

    for (int c0 = 0; c0 < segLen; c0 += CHUNK) {
        int cc = (segLen - c0 < CHUNK) ? (segLen - c0) : CHUNK;

        __syncthreads();                           // LDS reuse guard
        if (tid < CHUNK) {
            float4 p;
            if (tid < cc) p = proj_of(pos, opac, scl, qv, tv, g0 + c0 + tid);
            else { p.x = 0.f; p.y = 0.f; p.z = 0.f; p.w = 0.f; }  // pad -> U=0
            P_lds[tid] = p;
        } else {
            // threads 64..255 stage colors: ch = e>>6, g = e&63
            int e  = tid - 64;                     // 0..191 = 3*CHUNK
            int ch = e >> 6;
            int g  = e & 63;
            C_t[ch * CHUNK + g] = (g < cc) ? col[3 * (g0 + c0 + g) + ch] : 0.f;
        }
        __syncthreads();

        // Stage U2: e = g*128 + x; g wave-uniform -> P broadcast read;
        // write idx = (g>>1)*256 + 2x + (g&1): lane stride 2 -> 2-way free.
        for (int e = tid; e < CHUNK * 128; e += 256) {
            int x = e & 127, g = e >> 7;
            float4 p = P_lds[g];
            float dx = (float)x - p.x;
            U2[(g >> 1) * 256 + 2 * x + (g & 1)] =
                p.w * __builtin_amdgcn_exp2f(p.z * dx * dx);
        }
        // Stage V_t: e = g + 64*y (g lane-fast -> conflict-free writes).
        for (int e = tid; e < 16 * CHUNK; e += 256) {
            int g = e & 63, y = e >> 6;
            float4 p = P_lds[g];
            float dy = (float)(yb + y) - p.y;
            V_t[y * CHUNK + g] = __builtin_amdgcn_exp2f(p.z * dy * dy);
        }
        __syncthreads();

        const float* __restrict__ Up = U2 + 4 * xt;

        for (int jq = 0; jq < CHUNK / 4; ++jq) {   // 4 j (= 2 j-pairs) per iter
            float4 uA = *(const float4*)(Up + (2 * jq) * 256);        // jp0
            float4 uB = *(const float4*)(Up + (2 * jq) * 256 + 256);  // jp1
            float4 v0 = *(const float4*)(V_t + (wy + 0) * CHUNK + 4 * jq);
            float4 v1 = *(const float4*)(V_t + (wy + 1) * CHUNK + 4 * jq);
            float4 v2 = *(const float4*)(V_t + (wy + 2) * CHUNK + 4 * jq);
            float4 v3 = *(const float4*)(V_t + (wy + 3) * CHUNK + 4 * jq);
            float4 cr = *(const float4*)(C_t + 0 * CHUNK + 4 * jq);
            float4 cg = *(const float4*)(C_t + 1 * CHUNK + 4 * jq);
            float4 cb = *(const float4*)(C_t + 2 * CHUNK + 4 * jq);

            v2f uA0 = {uA.x, uA.y}, uA1 = {uA.z, uA.w};   // jp0: x0, x1
            v2f uB0 = {uB.x, uB.y}, uB1 = {uB.z, uB.w};   // jp1: x0, x1
            v2f crA = {cr.x, cr.y}, crB = {cr.z, cr.w};
            v2f cgA = {cg.x, cg.y}, cgB = {cg.z, cg.w};
            v2f cbA = {cb.x, cb.y}, cbB = {cb.z, cb.w};

            #define PXROW(yi, vv)                                           \
            {                                                               \
                v2f vA = {vv.x, vv.y}, vB = {vv.z, vv.w};                   \
                {                                                           \
                    v2f wA = pk_mul(uA0, vA), wB = pk_mul(uB0, vB);         \
                    pk_fma(accR[0][yi], wA, crA); pk_fma(accR[0][yi], wB, crB); \
                    pk_fma(accG[0][yi], wA, cgA); pk_fma(accG[0][yi], wB, cgB); \
                    pk_fma(accB[0][yi], wA, cbA); pk_fma(accB[0][yi], wB, cbB); \
                    pk_add(accD[0][yi], wA);      pk_add(accD[0][yi], wB);  \
                }                                                           \
                {                                                           \
                    v2f wA = pk_mul(uA1, vA), wB = pk_mul(uB1, vB);         \
                    pk_fma(accR[1][yi], wA, crA); pk_fma(accR[1][yi], wB, crB); \
                    pk_fma(accG[1][yi], wA, cgA); pk_fma(accG[1][yi], wB, cgB); \
                    pk_fma(accB[1][yi], wA, cbA); pk_fma(accB[1][yi], wB, cbB); \
                    pk_add(accD[1][yi], wA);      pk_add(accD[1][yi], wB);  \
                }                                                           \
            }

            PXROW(0, v0)
            PXROW(1, v1)
            PXROW(2, v2)
            PXROW(3, v3)
            #undef PXROW
        }
    }

    // Epilogue: horizontal-add the even/odd-j partials, store float4/px.
    size_t segBase = (size_t)blockIdx.y * HW_IMG + 2 * xt;
    #pragma unroll
    for (int yi = 0; yi < 4; ++yi) {
        size_t b = segBase + (size_t)(yb + wy + yi) * 128;
        float4 o0, o1;
        o0.x = accR[0][yi].x + accR[0][yi].y;
        o0.y = accG[0][yi].x + accG[0][yi].y;
        o0.z = accB[0][yi].x + accB[0][yi].y;
        o0.w = accD[0][yi].x + accD[0][yi].y;
        o1.x = accR[1][yi].x + accR[1][yi].y;
        o1.y = accG[1][yi].x + accG[1][yi].y;
        o1.z = accB[1][yi].x + accB[1][yi].y;
        o1.w = accD[1][yi].x + accD[1][yi].y;
        part[b] = o0; part[b + 1] = o1;
    }
}

// ---------------------------------------------------------------------------
// Fallback hot kernel (tiny-workspace path only): direct 2-D evaluation.
// ---------------------------------------------------------------------------
__global__ __launch_bounds__(256) void render_fb(
    const float* __restrict__ pos, const float* __restrict__ col,
    const float* __restrict__ opac, const float* __restrict__ scl,
    const float* __restrict__ qv, const float* __restrict__ tv,
    float4* __restrict__ part, int segLen)
{
    int p = blockIdx.x * 256 + threadIdx.x;
    float X = (float)(p & (W_IMG - 1));
    float Y = (float)(p >> 7);

    int g0 = blockIdx.y * segLen;
    float nr = 0.f, ng = 0.f, nb = 0.f, den = 0.f;
    for (int j = 0; j < segLen; ++j) {
        int g = g0 + j;
        float4 pg = proj_of(pos, opac, scl, qv, tv, g);
        float dx = X - pg.x;
        float dy = Y - pg.y;
        float d2 = fmaf(dx, dx, dy * dy);
        float e  = pg.w * __builtin_amdgcn_exp2f(pg.z * d2);
        nr  = fmaf(e, col[3*g+0], nr);
        ng  = fmaf(e, col[3*g+1], ng);
        nb  = fmaf(e, col[3*g+2], nb);
        den += e;
    }
    float4 o; o.x = nr; o.y = ng; o.z = nb; o.w = den;
    part[(size_t)blockIdx.y * HW_IMG + p] = o;
}

// ---------------------------------------------------------------------------
// Finalize: reduce segments, add n_chunks*EPS, divide, tiled/transposed fp32
// output: out[t, c, s/tile, s%tile], p = t*step + s, step = tile^2.
// ---------------------------------------------------------------------------
__global__ __launch_bounds__(256) void finalize_kernel(
    const float4* __restrict__ part, float* __restrict__ out,
    const int* __restrict__ chunk_gauss_p, const int* __restrict__ tile_hw_p,
    int N, int nseg)
{
    int p = blockIdx.x * 256 + threadIdx.x;

    float nr = 0.f, ng = 0.f, nb = 0.f, den = 0.f;
    #pragma unroll 8
    for (int s = 0; s < nseg; ++s) {
        float4 v = part[(size_t)s * HW_IMG + p];
        nr += v.x; ng += v.y; nb += v.z; den += v.w;
    }

    int cg = chunk_gauss_p[0];
    int n_chunks = (cg > 0) ? (N / cg) : 0;
    den += (float)n_chunks * 1e-8f;   // EPS added once per scan chunk

    int th   = tile_hw_p[0];
    int step = th * th;
    if (step <= 0 || step > HW_IMG) { th = 64; step = th * th; }
    int t  = p / step;
    int s2 = p - t * step;
    size_t base = (size_t)t * 3 * step + s2;

    out[base]            = nr / den;
    out[base + step]     = ng / den;
    out[base + 2 * step] = nb / den;
}

extern "C" void kernel_launch(void* const* d_in, const int* in_sizes, int n_in,
                              void* d_out, int out_size, void* d_ws, size_t ws_size,
                              hipStream_t stream)
{
    const float* pos  = (const float*)d_in[0];
    const float* col  = (const float*)d_in[1];
    const float* opac = (const float*)d_in[2];
    const float* scl  = (const float*)d_in[3];
    const float* qv   = (const float*)d_in[4];
    const float* tv   = (const float*)d_in[5];
    const int* tile_hw_p     = (const int*)d_in[6];
    const int* chunk_gauss_p = (const int*)d_in[7];

    int N = in_sizes[2];                 // one opacity per gaussian

    // Workspace: only part[S * HW] float4 (factors live in LDS).
    int S = 0;
    for (int cand = 128; cand >= 8; cand >>= 1) {
        if (N % cand == 0 &&
            (size_t)cand * HW_IMG * 16 <= ws_size) { S = cand; break; }
    }

    float4* part = (float4*)d_ws;

    if (S > 0) {
        dim3 grid(H_IMG / 16, S);
        gemm_fused<<<grid, 256, 0, stream>>>(
            pos, col, opac, scl, qv, tv, part, N / S);

        finalize_kernel<<<HW_IMG / 256, 256, 0, stream>>>(
            part, (float*)d_out, chunk_gauss_p, tile_hw_p, N, S);
    } else {
        int nseg = 16;
        while (nseg > 1 &&
               ((size_t)nseg * HW_IMG * 16 > ws_size || (N % nseg) != 0))
            nseg >>= 1;

        dim3 grid(HW_IMG / 256, nseg);
        render_fb<<<grid, 256, 0, stream>>>(pos, col, opac, scl, qv, tv, part, N / nseg);

        finalize_kernel<<<HW_IMG / 256, 256, 0, stream>>>(
            part, (float*)d_out, chunk_gauss_p, tile_hw_p, N, nseg);
    }
}